// Round 2
// baseline (165.464 us; speedup 1.0000x reference)
//
#include <hip/hip_runtime.h>
#include <math.h>

namespace {

constexpr int B_ = 8, L_ = 4096, C_ = 128, K_ = 7;
constexpr int LP = L_ - K_ + 1;        // 4090
constexpr int BM = 64;                 // l-tile
constexpr int BD = 32;                 // d-tile (output channels)
constexpr int BK = 32;                 // cin chunk
constexpr int CK = C_ * K_;            // 896

// W[d][cin][k] -> Wt[cin][k][d]   (k-major so GEMM B-tiles load/store wide)
__global__ void transpose_w(const float* __restrict__ W, float* __restrict__ Wt) {
    int o = blockIdx.x * 256 + threadIdx.x;     // output index, coalesced writes
    if (o >= C_ * CK) return;
    int d   = o % C_;
    int k   = (o / C_) % K_;
    int cin = o / CK;
    Wt[o] = W[d * CK + cin * K_ + k];
}

__device__ __forceinline__ float fast_tanh(float v) {
    float a = fabsf(v);
    float e = __expf(2.0f * a);
    float t = 1.0f - 2.0f / (e + 1.0f);   // a large -> e=inf -> t=1
    return v < 0.0f ? -t : t;
}

template <bool USE_WT>
__global__ __launch_bounds__(256, 2) void sidechain(const float* __restrict__ x,
                                                    const float* __restrict__ W,
                                                    float* __restrict__ out) {
    __shared__ float As[BK][BM + 4];   // [cin][l], stride 68 floats (272B, 16B-aligned rows)
    __shared__ float Bs[BK][K_ * BD];  // [cin][k][d_local], row = 224 floats

    const int mtile = blockIdx.x;      // 64 l-tiles per batch
    const int b  = mtile >> 6;
    const int l0 = (mtile & 63) * BM;
    const int d0 = blockIdx.y * BD;

    const int tid = threadIdx.x;
    const int tx = tid & 15;           // d-pair group: d = d0 + 2*tx + dd
    const int ty = tid >> 4;           // l group: l = l0 + 4*ty + j

    const float* xb = x + (size_t)b * (L_ * C_);

    float acc[4][2][K_];
#pragma unroll
    for (int j = 0; j < 4; ++j)
#pragma unroll
        for (int dd = 0; dd < 2; ++dd)
#pragma unroll
            for (int k = 0; k < K_; ++k) acc[j][dd][k] = 0.0f;

    for (int kc = 0; kc < C_; kc += BK) {
        // ---- A tile (transposed): As[c][l] = x[l0+6+l][kc+c],  l in 0..63, c in 0..31
        {
            int r  = tid >> 3;         // l-index 0..31 (then +32)
            int cg = (tid & 7) * 4;    // c-group
#pragma unroll
            for (int half = 0; half < 2; ++half) {
                int ll = r + half * 32;
                int xr = l0 + 6 + ll;
                if (xr > L_ - 1) xr = L_ - 1;        // clamp; clamped rows are never used
                const float4 v = *reinterpret_cast<const float4*>(&xb[xr * C_ + kc + cg]);
                As[cg + 0][ll] = v.x;
                As[cg + 1][ll] = v.y;
                As[cg + 2][ll] = v.z;
                As[cg + 3][ll] = v.w;
            }
        }
        // ---- B tile: Bs[cin][k*32 + dl] ,  32 cin x 7 k x 32 d  (1792 float4 slots)
        {
#pragma unroll
            for (int p = 0; p < 7; ++p) {
                int s   = tid + p * 256;       // 0..1791
                int cin = s / 56;
                int rem = s % 56;
                int k   = rem >> 3;
                int c4  = (rem & 7) * 4;
                float4 v;
                if (USE_WT) {
                    v = *reinterpret_cast<const float4*>(
                        &W[(size_t)(kc + cin) * CK + k * C_ + d0 + c4]);
                } else {
                    float* vv = reinterpret_cast<float*>(&v);
#pragma unroll
                    for (int q = 0; q < 4; ++q)
                        vv[q] = W[(size_t)(d0 + c4 + q) * CK + (kc + cin) * K_ + k];
                }
                *reinterpret_cast<float4*>(&Bs[cin][k * BD + c4]) = v;
            }
        }
        __syncthreads();

#pragma unroll
        for (int cin = 0; cin < BK; ++cin) {
            const float4 av = *reinterpret_cast<const float4*>(&As[cin][4 * ty]);
            const float a[4] = {av.x, av.y, av.z, av.w};
            float2 bv[K_];
#pragma unroll
            for (int k = 0; k < K_; ++k)
                bv[k] = *reinterpret_cast<const float2*>(&Bs[cin][k * BD + 2 * tx]);
#pragma unroll
            for (int j = 0; j < 4; ++j)
#pragma unroll
                for (int k = 0; k < K_; ++k) {
                    acc[j][0][k] = fmaf(a[j], bv[k].x, acc[j][0][k]);
                    acc[j][1][k] = fmaf(a[j], bv[k].y, acc[j][1][k]);
                }
        }
        __syncthreads();
    }

    // ---- epilogue: out[b,l,d] = sum_k x[b,l+k,d] * tanh(gate[l,d,k])
#pragma unroll
    for (int j = 0; j < 4; ++j) {
        int l = l0 + 4 * ty + j;
        if (l >= LP) continue;
        float s0 = 0.0f, s1 = 0.0f;
#pragma unroll
        for (int k = 0; k < K_; ++k) {
            const float2 xl = *reinterpret_cast<const float2*>(&xb[(l + k) * C_ + d0 + 2 * tx]);
            s0 = fmaf(xl.x, fast_tanh(acc[j][0][k]), s0);
            s1 = fmaf(xl.y, fast_tanh(acc[j][1][k]), s1);
        }
        float* o = &out[((size_t)b * LP + l) * C_ + d0 + 2 * tx];
        o[0] = s0;
        o[1] = s1;
    }
}

} // namespace

extern "C" void kernel_launch(void* const* d_in, const int* in_sizes, int n_in,
                              void* d_out, int out_size, void* d_ws, size_t ws_size,
                              hipStream_t stream) {
    const float* x = (const float*)d_in[0];
    const float* w = (const float*)d_in[1];
    float* out     = (float*)d_out;

    const size_t wt_bytes = (size_t)C_ * CK * sizeof(float);
    dim3 grid(B_ * ((LP + BM - 1) / BM), C_ / BD);

    if (ws_size >= wt_bytes) {
        float* wt = (float*)d_ws;
        transpose_w<<<dim3((C_ * CK + 255) / 256), dim3(256), 0, stream>>>(w, wt);
        sidechain<true><<<grid, dim3(256), 0, stream>>>(x, wt, out);
    } else {
        sidechain<false><<<grid, dim3(256), 0, stream>>>(x, w, out);
    }
}

// Round 3
// 108.662 us; speedup vs baseline: 1.5227x; 1.5227x over previous
//
#include <hip/hip_runtime.h>
#include <hip/hip_bf16.h>
#include <math.h>

namespace {

constexpr int B_ = 8, L_ = 4096, C_ = 128, K_ = 7;
constexpr int LP = L_ - K_ + 1;        // 4090
constexpr int CK = C_ * K_;            // 896

typedef __attribute__((ext_vector_type(8))) short short8v;
typedef __attribute__((ext_vector_type(4))) float f32x4;
typedef __attribute__((ext_vector_type(4))) unsigned int uint4v;

__device__ __forceinline__ unsigned short bf16_rne(float f) {
    __hip_bfloat16 h = __float2bfloat16(f);
    return *reinterpret_cast<unsigned short*>(&h);
}
__device__ __forceinline__ float bf16_to_f(unsigned short u) {
    __hip_bfloat16 h = *reinterpret_cast<__hip_bfloat16*>(&u);
    return __bfloat162float(h);
}

__device__ __forceinline__ float fast_tanh(float v) {
    float a = fabsf(v);
    float e = __expf(2.0f * a);
    float t = 1.0f - 2.0f / (e + 1.0f);
    return v < 0.0f ? -t : t;
}

// x (fp32) -> xhi, xlo (bf16 hi/lo split), 4 elems/thread
__global__ void convert_x(const float* __restrict__ x, unsigned short* __restrict__ xhi,
                          unsigned short* __restrict__ xlo, int n4) {
    int i = blockIdx.x * 256 + threadIdx.x;
    if (i >= n4) return;
    float4 v = reinterpret_cast<const float4*>(x)[i];
    ushort4 h, l;
    float* vv = reinterpret_cast<float*>(&v);
    unsigned short* hh = reinterpret_cast<unsigned short*>(&h);
    unsigned short* ll = reinterpret_cast<unsigned short*>(&l);
#pragma unroll
    for (int q = 0; q < 4; ++q) {
        hh[q] = bf16_rne(vv[q]);
        ll[q] = bf16_rne(vv[q] - bf16_to_f(hh[q]));
    }
    reinterpret_cast<ushort4*>(xhi)[i] = h;
    reinterpret_cast<ushort4*>(xlo)[i] = l;
}

// W[d][cin][k] -> Wb[k][d][cin] hi/lo bf16
__global__ void convert_w(const float* __restrict__ W, unsigned short* __restrict__ whi,
                          unsigned short* __restrict__ wlo) {
    int o = blockIdx.x * 256 + threadIdx.x;
    if (o >= C_ * CK) return;
    int cin = o & 127;
    int d   = (o >> 7) & 127;
    int k   = o >> 14;
    float v = W[d * CK + cin * K_ + k];
    unsigned short h = bf16_rne(v);
    whi[o] = h;
    wlo[o] = bf16_rne(v - bf16_to_f(h));
}

// ---- main fused kernel: 256 l-rows x 16 d per block, 4 waves x 64 rows
__global__ __launch_bounds__(256, 2) void sidechain_mfma(
        const float* __restrict__ x, const unsigned short* __restrict__ xhi,
        const unsigned short* __restrict__ xlo, const unsigned short* __restrict__ whi,
        const unsigned short* __restrict__ wlo, float* __restrict__ out) {
    __shared__ unsigned short BsHi[7 * 16 * C_];
    __shared__ unsigned short BsLo[7 * 16 * C_];

    const int tid = threadIdx.x;
    const int b  = blockIdx.x >> 4;
    const int l0 = (blockIdx.x & 15) * 256;
    const int d0 = blockIdx.y * 16;

    // ---- stage W tile into LDS, granule-swizzled (g ^= d&15) for conflict-free frag reads
    {
        int dl = tid >> 4;         // 0..15 (d row)
        int g  = tid & 15;         // 16B granule = 8 cin
        int gp = g ^ dl;
#pragma unroll
        for (int k = 0; k < 7; ++k) {
            const uint4v hv = *reinterpret_cast<const uint4v*>(&whi[((k * C_ + d0 + dl) * C_) + g * 8]);
            const uint4v lv = *reinterpret_cast<const uint4v*>(&wlo[((k * C_ + d0 + dl) * C_) + g * 8]);
            *reinterpret_cast<uint4v*>(&BsHi[(k * 16 + dl) * C_ + gp * 8]) = hv;
            *reinterpret_cast<uint4v*>(&BsLo[(k * 16 + dl) * C_ + gp * 8]) = lv;
        }
    }

    const int wv   = tid >> 6;
    const int lane = tid & 63;
    const int rA   = lane & 15;    // A row / D col / B col
    const int kg   = lane >> 4;    // 0..3

    // ---- A fragments in registers: 4 m-tiles x 4 k-steps, hi+lo
    short8v Ahi[4][4], Alo[4][4];
    const size_t xbase = (size_t)b * (L_ * C_);
#pragma unroll
    for (int mt = 0; mt < 4; ++mt) {
        int r = l0 + 6 + wv * 64 + mt * 16 + rA;
        if (r > L_ - 1) r = L_ - 1;            // clamped rows feed masked-out outputs only
#pragma unroll
        for (int ks = 0; ks < 4; ++ks) {
            int c0 = ks * 32 + kg * 8;
            Ahi[mt][ks] = *reinterpret_cast<const short8v*>(&xhi[xbase + (size_t)r * C_ + c0]);
            Alo[mt][ks] = *reinterpret_cast<const short8v*>(&xlo[xbase + (size_t)r * C_ + c0]);
        }
    }
    __syncthreads();

    f32x4 oacc[4];
#pragma unroll
    for (int mt = 0; mt < 4; ++mt) oacc[mt] = (f32x4)(0.0f);

    const int dcol = d0 + rA;
    const float* xb = x + xbase;

#pragma unroll
    for (int nt = 0; nt < 7; ++nt) {           // n-tile == tap k
        f32x4 acc[4];
#pragma unroll
        for (int mt = 0; mt < 4; ++mt) acc[mt] = (f32x4)(0.0f);
#pragma unroll
        for (int ks = 0; ks < 4; ++ks) {
            int gp = (ks * 4 + kg) ^ rA;
            const short8v Bh = *reinterpret_cast<const short8v*>(&BsHi[(nt * 16 + rA) * C_ + gp * 8]);
            const short8v Bl = *reinterpret_cast<const short8v*>(&BsLo[(nt * 16 + rA) * C_ + gp * 8]);
#pragma unroll
            for (int mt = 0; mt < 4; ++mt) {
                acc[mt] = __builtin_amdgcn_mfma_f32_16x16x32_bf16(Ahi[mt][ks], Bh, acc[mt], 0, 0, 0);
                acc[mt] = __builtin_amdgcn_mfma_f32_16x16x32_bf16(Ahi[mt][ks], Bl, acc[mt], 0, 0, 0);
                acc[mt] = __builtin_amdgcn_mfma_f32_16x16x32_bf16(Alo[mt][ks], Bh, acc[mt], 0, 0, 0);
            }
        }
        // fused FIR epilogue for tap nt
#pragma unroll
        for (int mt = 0; mt < 4; ++mt) {
#pragma unroll
            for (int r = 0; r < 4; ++r) {
                int l = l0 + wv * 64 + mt * 16 + kg * 4 + r;
                int xr = l + nt; if (xr > L_ - 1) xr = L_ - 1;
                float xv = xb[(size_t)xr * C_ + dcol];
                oacc[mt][r] = fmaf(xv, fast_tanh(acc[mt][r]), oacc[mt][r]);
            }
        }
    }
#pragma unroll
    for (int mt = 0; mt < 4; ++mt) {
#pragma unroll
        for (int r = 0; r < 4; ++r) {
            int l = l0 + wv * 64 + mt * 16 + kg * 4 + r;
            if (l < LP) out[((size_t)b * LP + l) * C_ + dcol] = oacc[mt][r];
        }
    }
}

// ================= fp32 vector fallback (used only if ws too small) =================
__global__ __launch_bounds__(256, 2) void sidechain_vec(const float* __restrict__ x,
                                                        const float* __restrict__ W,
                                                        float* __restrict__ out) {
    __shared__ float As[32][68];
    __shared__ float Bs[32][K_ * 32];
    const int b  = blockIdx.x >> 6;
    const int l0 = (blockIdx.x & 63) * 64;
    const int d0 = blockIdx.y * 32;
    const int tid = threadIdx.x;
    const int tx = tid & 15, ty = tid >> 4;
    const float* xb = x + (size_t)b * (L_ * C_);
    float acc[4][2][K_];
#pragma unroll
    for (int j = 0; j < 4; ++j)
#pragma unroll
        for (int dd = 0; dd < 2; ++dd)
#pragma unroll
            for (int k = 0; k < K_; ++k) acc[j][dd][k] = 0.0f;
    for (int kc = 0; kc < C_; kc += 32) {
        int r = tid >> 3, cg = (tid & 7) * 4;
#pragma unroll
        for (int half = 0; half < 2; ++half) {
            int ll = r + half * 32;
            int xr = l0 + 6 + ll; if (xr > L_ - 1) xr = L_ - 1;
            const float4 v = *reinterpret_cast<const float4*>(&xb[xr * C_ + kc + cg]);
            As[cg + 0][ll] = v.x; As[cg + 1][ll] = v.y; As[cg + 2][ll] = v.z; As[cg + 3][ll] = v.w;
        }
#pragma unroll
        for (int p = 0; p < 7; ++p) {
            int s = tid + p * 256;
            int cin = s / 56, rem = s % 56, k = rem >> 3, c4 = (rem & 7) * 4;
            float4 v; float* vv = reinterpret_cast<float*>(&v);
#pragma unroll
            for (int q = 0; q < 4; ++q)
                vv[q] = W[(size_t)(d0 + c4 + q) * CK + (kc + cin) * K_ + k];
            *reinterpret_cast<float4*>(&Bs[cin][k * 32 + c4]) = v;
        }
        __syncthreads();
#pragma unroll
        for (int cin = 0; cin < 32; ++cin) {
            const float4 av = *reinterpret_cast<const float4*>(&As[cin][4 * ty]);
            const float a[4] = {av.x, av.y, av.z, av.w};
            float2 bv[K_];
#pragma unroll
            for (int k = 0; k < K_; ++k)
                bv[k] = *reinterpret_cast<const float2*>(&Bs[cin][k * 32 + 2 * tx]);
#pragma unroll
            for (int j = 0; j < 4; ++j)
#pragma unroll
                for (int k = 0; k < K_; ++k) {
                    acc[j][0][k] = fmaf(a[j], bv[k].x, acc[j][0][k]);
                    acc[j][1][k] = fmaf(a[j], bv[k].y, acc[j][1][k]);
                }
        }
        __syncthreads();
    }
#pragma unroll
    for (int j = 0; j < 4; ++j) {
        int l = l0 + 4 * ty + j;
        if (l >= LP) continue;
        float s0 = 0.0f, s1 = 0.0f;
#pragma unroll
        for (int k = 0; k < K_; ++k) {
            const float2 xl = *reinterpret_cast<const float2*>(&xb[(l + k) * C_ + d0 + 2 * tx]);
            s0 = fmaf(xl.x, fast_tanh(acc[j][0][k]), s0);
            s1 = fmaf(xl.y, fast_tanh(acc[j][1][k]), s1);
        }
        float* o = &out[((size_t)b * LP + l) * C_ + d0 + 2 * tx];
        o[0] = s0; o[1] = s1;
    }
}

} // namespace

extern "C" void kernel_launch(void* const* d_in, const int* in_sizes, int n_in,
                              void* d_out, int out_size, void* d_ws, size_t ws_size,
                              hipStream_t stream) {
    const float* x = (const float*)d_in[0];
    const float* w = (const float*)d_in[1];
    float* out     = (float*)d_out;

    const size_t n_x   = (size_t)B_ * L_ * C_;            // 4194304
    const size_t n_w   = (size_t)C_ * CK;                 // 114688
    const size_t bytes_x = n_x * 2;                       // per precision
    const size_t bytes_w = n_w * 2;
    const size_t need = 2 * bytes_x + 2 * bytes_w;        // ~17.2 MB

    if (ws_size >= need) {
        unsigned short* xhi = (unsigned short*)d_ws;
        unsigned short* xlo = xhi + n_x;
        unsigned short* whi = xlo + n_x;
        unsigned short* wlo = whi + n_w;
        convert_x<<<dim3((int)(n_x / 4 + 255) / 256), dim3(256), 0, stream>>>(x, xhi, xlo, (int)(n_x / 4));
        convert_w<<<dim3((int)(n_w + 255) / 256), dim3(256), 0, stream>>>(w, whi, wlo);
        dim3 grid(B_ * 16, C_ / 16);
        sidechain_mfma<<<grid, dim3(256), 0, stream>>>(x, xhi, xlo, whi, wlo, out);
    } else {
        dim3 grid(B_ * 64, C_ / 32);
        sidechain_vec<<<grid, dim3(256), 0, stream>>>(x, w, out);
    }
}